// Round 10
// baseline (280.152 us; speedup 1.0000x reference)
//
#include <hip/hip_runtime.h>

#define IMG_H 512
#define IMG_W 512
#define N_IMG 24                          // B*C
#define NPIX (N_IMG * IMG_H * IMG_W)      // 6291456
#define ROWS_PT 4                         // center rows per thread
#define BLOCK 256
#define NBLOCKS 6144                      // 24 img * 128 slabs * 2 col-halves

// scalar dword load, saddr form: per-lane byte offset + uniform row base.
#define GLOAD(dst, off, base) \
    asm volatile("global_load_dword %0, %1, %2" : "=v"(dst) : "v"(off), "s"(base));

// partial vmem wait + scheduler fence
#define VMWAIT(N)                                             \
    asm volatile("s_waitcnt vmcnt(" #N ")" ::: "memory");     \
    __builtin_amdgcn_sched_barrier(0)

__device__ __forceinline__ int reflect_b(int x) {   // PAD=2 reflect, rows
    int a = x < 0 ? -x : x;
    int b = 2 * IMG_H - 2 - a;
    return a < b ? a : b;
}

// per loaded-row register set: 5 shifts x 2 inputs, all named scalars
#define DECL_ROW(i) \
    float pL2_##i, pL1_##i, pC_##i, pR1_##i, pR2_##i, \
          gL2_##i, gL1_##i, gC_##i, gR1_##i, gR2_##i;

#define LOAD_ROW(i, pb, gb) \
    GLOAD(pL2_##i, o_m2, pb) GLOAD(pL1_##i, o_m1, pb) GLOAD(pC_##i, o_c, pb) \
    GLOAD(pR1_##i, o_p1, pb) GLOAD(pR2_##i, o_p2, pb) \
    GLOAD(gL2_##i, o_m2, gb) GLOAD(gL1_##i, o_m1, gb) GLOAD(gC_##i, o_c, gb) \
    GLOAD(gR1_##i, o_p1, gb) GLOAD(gR2_##i, o_p2, gb)

// branchless reflect fixups (only edge-col lanes change; same-lane selects)
#define FIX_ROW(i) {                                                        \
    pL1_##i = l0 ? pR1_##i : pL1_##i;  gL1_##i = l0 ? gR1_##i : gL1_##i;    \
    float tp = l1 ? pC_##i : pL2_##i;  float tg = l1 ? gC_##i : gL2_##i;    \
    pL2_##i = l0 ? pR2_##i : tp;       gL2_##i = l0 ? gR2_##i : tg;         \
    pR1_##i = l63 ? pL1_##i : pR1_##i; gR1_##i = l63 ? gL1_##i : gR1_##i;   \
    float up = l62 ? pC_##i : pR2_##i; float ug = l62 ? gC_##i : gR2_##i;   \
    pR2_##i = l63 ? pL2_##i : up;      gR2_##i = l63 ? gL2_##i : ug; }

// one offset: ballot both inputs, xor masks, popcount (SALU), accumulate
#define CMP1(psrc, gsrc) \
    cnt += __popcll(__ballot(psrc < pcen) ^ __ballot(gsrc < gcen));

#define CMP_ROW5(i) \
    CMP1(pL2_##i, gL2_##i) CMP1(pL1_##i, gL1_##i) CMP1(pC_##i, gC_##i) \
    CMP1(pR1_##i, gR1_##i) CMP1(pR2_##i, gR2_##i)
#define CMP_ROW4(i) \
    CMP1(pL2_##i, gL2_##i) CMP1(pL1_##i, gL1_##i) \
    CMP1(pR1_##i, gR1_##i) CMP1(pR2_##i, gR2_##i)

// center = loaded row c; window rows a..e = c-2..c+2 (24 offsets)
#define DO_CENTER(a, b, c, d, e) {                     \
    const float pcen = pC_##c, gcen = gC_##c;          \
    CMP_ROW5(a) CMP_ROW5(b) CMP_ROW4(c) CMP_ROW5(d) CMP_ROW5(e) }

__global__ void census_init(unsigned int* __restrict__ ws) {
    ws[0] = 0u;
    ws[1] = 0u;
}

__global__ __launch_bounds__(BLOCK) void census_main(
    const float* __restrict__ pred, const float* __restrict__ gt,
    float* __restrict__ out, unsigned int* __restrict__ ws)
{
    const int b   = blockIdx.x;
    const int tid = threadIdx.x;

    // block -> (img, 4-row slab, 256-col half); wave = 64 consecutive cols
    const int col  = ((b & 1) << 8) | tid;       // 0..511, lane-contiguous
    const int s    = b >> 1;
    const int slab = s & 127;
    const int img  = s >> 7;
    const int h0   = slab * ROWS_PT;

    const float* __restrict__ pimg = pred + (size_t)img * IMG_H * IMG_W;
    const float* __restrict__ gimg = gt   + (size_t)img * IMG_H * IMG_W;

    // per-lane byte offsets for the 5 column shifts (clamped in-bounds;
    // edge lanes' values corrected by FIX_ROW selects)
    const int o_m2 = 4 * max(col - 2, 0);
    const int o_m1 = 4 * max(col - 1, 0);
    const int o_c  = 4 * col;
    const int o_p1 = 4 * min(col + 1, IMG_W - 1);
    const int o_p2 = 4 * min(col + 2, IMG_W - 1);

    const bool l0  = (col == 0);
    const bool l1  = (col == 1);
    const bool l62 = (col == IMG_W - 2);
    const bool l63 = (col == IMG_W - 1);

    DECL_ROW(0) DECL_ROW(1) DECL_ROW(2) DECL_ROW(3)
    DECL_ROW(4) DECL_ROW(5) DECL_ROW(6) DECL_ROW(7)

    // issue ALL 80 loads (rows h0-2 .. h0+5, reflected), volatile order
    {
        const float* pb; const float* gb;
        pb = pimg + reflect_b(h0 - 2) * IMG_W; gb = gimg + reflect_b(h0 - 2) * IMG_W;
        LOAD_ROW(0, pb, gb)
        pb = pimg + reflect_b(h0 - 1) * IMG_W; gb = gimg + reflect_b(h0 - 1) * IMG_W;
        LOAD_ROW(1, pb, gb)
        pb = pimg + (h0 + 0) * IMG_W;          gb = gimg + (h0 + 0) * IMG_W;
        LOAD_ROW(2, pb, gb)
        pb = pimg + (h0 + 1) * IMG_W;          gb = gimg + (h0 + 1) * IMG_W;
        LOAD_ROW(3, pb, gb)
        pb = pimg + (h0 + 2) * IMG_W;          gb = gimg + (h0 + 2) * IMG_W;
        LOAD_ROW(4, pb, gb)
        pb = pimg + (h0 + 3) * IMG_W;          gb = gimg + (h0 + 3) * IMG_W;
        LOAD_ROW(5, pb, gb)
        pb = pimg + reflect_b(h0 + 4) * IMG_W; gb = gimg + reflect_b(h0 + 4) * IMG_W;
        LOAD_ROW(6, pb, gb)
        pb = pimg + reflect_b(h0 + 5) * IMG_W; gb = gimg + reflect_b(h0 + 5) * IMG_W;
        LOAD_ROW(7, pb, gb)
    }

    int cnt = 0;   // wave-uniform hamming accumulator

    VMWAIT(30);    // rows 0..4 landed (50 of 80 retired)
    FIX_ROW(0) FIX_ROW(1) FIX_ROW(2) FIX_ROW(3) FIX_ROW(4)
    DO_CENTER(0, 1, 2, 3, 4)      // center row h0

    VMWAIT(20);    // row 5 landed
    FIX_ROW(5)
    DO_CENTER(1, 2, 3, 4, 5)      // h0+1

    VMWAIT(10);    // row 6 landed
    FIX_ROW(6)
    DO_CENTER(2, 3, 4, 5, 6)      // h0+2

    VMWAIT(0);     // row 7 landed
    FIX_ROW(7)
    DO_CENTER(3, 4, 5, 6, 7)      // h0+3

    // ---- block reduction: cnt is wave-uniform (covers 64 px x 4 rows) ----
    __shared__ int wave_sums[BLOCK / 64];
    const int lane = tid & 63;
    const int wid  = tid >> 6;
    if (lane == 0) wave_sums[wid] = cnt;
    __syncthreads();

    if (tid == 0) {
        int total = wave_sums[0] + wave_sums[1] + wave_sums[2] + wave_sums[3];
        atomicAdd(&ws[0], (unsigned int)total);
        __threadfence();
        unsigned int r = atomicAdd(&ws[1], 1u);
        if (r == (unsigned int)(NBLOCKS - 1)) {
            unsigned int tot = atomicAdd(&ws[0], 0u);
            out[0] = (float)((double)tot / (double)NPIX);
        }
    }
}

extern "C" void kernel_launch(void* const* d_in, const int* in_sizes, int n_in,
                              void* d_out, int out_size, void* d_ws, size_t ws_size,
                              hipStream_t stream) {
    const float* pred = (const float*)d_in[0];
    const float* gt   = (const float*)d_in[1];
    float* out        = (float*)d_out;
    unsigned int* ws  = (unsigned int*)d_ws;

    census_init<<<1, 1, 0, stream>>>(ws);
    census_main<<<NBLOCKS, BLOCK, 0, stream>>>(pred, gt, out, ws);
}

// Round 11
// 186.350 us; speedup vs baseline: 1.5034x; 1.5034x over previous
//
#include <hip/hip_runtime.h>

#define IMG_H 512
#define IMG_W 512
#define N_IMG 24                          // B*C
#define NPIX (N_IMG * IMG_H * IMG_W)      // 6291456
#define BLOCK 256
#define NBLOCKS (N_IMG * IMG_H / 4)      // 3072: block = 4 rows of one image

__device__ __forceinline__ int reflect_b(int x) {   // PAD=2 reflect, rows
    int a = x < 0 ? -x : x;
    int b = 2 * IMG_H - 2 - a;
    return a < b ? a : b;
}

// Build the 12-float window (cols 8L-2 .. 8L+9, reflect-padded) of one image
// row for lane L. Two ALIGNED dwordx4 + 4 shfl (halo from neighbor lanes;
// wave spans the whole 512-px row so lane+-1 is always the right neighbor)
// + 4 same-lane cndmask reflect fixups at lanes 0/63.
__device__ __forceinline__ void mkrow(const float* __restrict__ rowbase,
                                      int lane, float w[12]) {
    const float4 A = *(const float4*)(rowbase + 8 * lane);      // cols 8L..8L+3
    const float4 B = *(const float4*)(rowbase + 8 * lane + 4);  // cols 8L+4..8L+7
    const float lm2 = __shfl(B.z, lane - 1, 64);   // col 8L-2
    const float lm1 = __shfl(B.w, lane - 1, 64);   // col 8L-1
    const float rp1 = __shfl(A.x, lane + 1, 64);   // col 8L+8
    const float rp2 = __shfl(A.y, lane + 1, 64);   // col 8L+9
    const bool e0 = (lane == 0), e63 = (lane == 63);
    w[0] = e0 ? A.z : lm2;     // col -2 -> 2
    w[1] = e0 ? A.y : lm1;     // col -1 -> 1
    w[2] = A.x; w[3] = A.y; w[4] = A.z; w[5] = A.w;
    w[6] = B.x; w[7] = B.y; w[8] = B.z; w[9] = B.w;
    w[10] = e63 ? B.z : rp1;   // col 512 -> 510
    w[11] = e63 ? B.y : rp2;   // col 513 -> 509
}

__global__ void census_init(unsigned int* __restrict__ ws) {
    ws[0] = 0u;
    ws[1] = 0u;
}

__global__ __launch_bounds__(BLOCK, 4) void census_main(
    const float* __restrict__ pred, const float* __restrict__ gt,
    float* __restrict__ out, unsigned int* __restrict__ ws)
{
    const int tid  = threadIdx.x;
    const int lane = tid & 63;
    const int wave = tid >> 6;

    // block -> (img, 4-row group); wave w handles center row hb+w
    const int b    = blockIdx.x;
    const int img  = b >> 7;              // / 128
    const int h    = ((b & 127) << 2) | wave;   // center row 0..511

    const float* __restrict__ pimg = pred + (size_t)img * IMG_H * IMG_W;
    const float* __restrict__ gimg = gt   + (size_t)img * IMG_H * IMG_W;

    // Center row first (it is also the dy=0 comparison row).
    float pc[12], gc[12];
    mkrow(pimg + (size_t)h * IMG_W, lane, pc);
    mkrow(gimg + (size_t)h * IMG_W, lane, gc);

    int cnt = 0;

    #pragma unroll
    for (int dy = -2; dy <= 2; ++dy) {
        float pr[12], gr[12];
        if (dy == 0) {
            #pragma unroll
            for (int k = 0; k < 12; ++k) { pr[k] = pc[k]; gr[k] = gc[k]; }
        } else {
            const int ry = reflect_b(h + dy);
            mkrow(pimg + (size_t)ry * IMG_W, lane, pr);
            mkrow(gimg + (size_t)ry * IMG_W, lane, gr);
        }
        #pragma unroll
        for (int dx = 0; dx < 5; ++dx) {
            if (dy == 0 && dx == 2) continue;   // window center
            #pragma unroll
            for (int k = 0; k < 8; ++k) {
                // pixel col 8L+k, neighbor col +(dx-2) -> window idx k+dx
                cnt += (int)((pr[k + dx] < pc[2 + k]) != (gr[k + dx] < gc[2 + k]));
            }
        }
    }

    // ---- exact integer reduction ----
    #pragma unroll
    for (int off = 32; off > 0; off >>= 1)
        cnt += __shfl_down(cnt, off, 64);

    __shared__ int wave_sums[BLOCK / 64];
    if (lane == 0) wave_sums[wave] = cnt;
    __syncthreads();

    if (tid == 0) {
        int total = wave_sums[0] + wave_sums[1] + wave_sums[2] + wave_sums[3];
        atomicAdd(&ws[0], (unsigned int)total);
        __threadfence();
        unsigned int r = atomicAdd(&ws[1], 1u);
        if (r == (unsigned int)(NBLOCKS - 1)) {
            unsigned int tot = atomicAdd(&ws[0], 0u);
            out[0] = (float)((double)tot / (double)NPIX);
        }
    }
}

extern "C" void kernel_launch(void* const* d_in, const int* in_sizes, int n_in,
                              void* d_out, int out_size, void* d_ws, size_t ws_size,
                              hipStream_t stream) {
    const float* pred = (const float*)d_in[0];
    const float* gt   = (const float*)d_in[1];
    float* out        = (float*)d_out;
    unsigned int* ws  = (unsigned int*)d_ws;

    census_init<<<1, 1, 0, stream>>>(ws);
    census_main<<<NBLOCKS, BLOCK, 0, stream>>>(pred, gt, out, ws);
}

// Round 12
// 135.800 us; speedup vs baseline: 2.0630x; 1.3722x over previous
//
#include <hip/hip_runtime.h>

#define IMG_H 512
#define IMG_W 512
#define N_IMG 24                          // B*C
#define NPIX (N_IMG * IMG_H * IMG_W)      // 6291456
#define TH 8                              // center rows per block
#define LR (TH + 4)                       // 12 staged rows
#define BLOCK 256
#define NBLOCKS (N_IMG * IMG_H / TH)      // 1536

#if __has_builtin(__builtin_amdgcn_ballot_w64)
#define BALLOT(x) __builtin_amdgcn_ballot_w64(x)
#else
#define BALLOT(x) __ballot(x)
#endif

__device__ __forceinline__ int reflect_row(int x) {   // PAD=2 reflect
    int a = x < 0 ? -x : x;
    int b = 2 * IMG_H - 2 - a;
    return a < b ? a : b;
}

__global__ void census_init(unsigned int* __restrict__ ws) {
    ws[0] = 0u;
    ws[1] = 0u;
}

__global__ __launch_bounds__(BLOCK) void census_main(
    const float* __restrict__ pred, const float* __restrict__ gt,
    float* __restrict__ out, unsigned int* __restrict__ ws)
{
    __shared__ float lsp[LR][IMG_W];      // 24 KB
    __shared__ float lsg[LR][IMG_W];      // 24 KB
    __shared__ int wave_sums[BLOCK / 64];

    const int tid = threadIdx.x;
    const int b   = blockIdx.x;
    const int img = b >> 6;               // 64 row-groups per image
    const int hb  = (b & 63) * TH;        // first center row of tile

    const float* __restrict__ pimg = pred + (size_t)img * IMG_H * IMG_W;
    const float* __restrict__ gimg = gt   + (size_t)img * IMG_H * IMG_W;

    // ---- stage 12 rows x 512 cols x 2 inputs, coalesced float4 ----
    #pragma unroll
    for (int k = 0; k < 6; ++k) {
        const int idx = tid + k * BLOCK;   // 0..1535
        const int row = idx >> 7;          // 0..11
        const int c4  = (idx & 127) << 2;  // 0..508
        const int gy  = reflect_row(hb - 2 + row);
        *(float4*)&lsp[row][c4] = *(const float4*)(pimg + gy * IMG_W + c4);
        *(float4*)&lsg[row][c4] = *(const float4*)(gimg + gy * IMG_W + c4);
    }
    __syncthreads();

    // ---- wave-ballot census: unit = 4 center rows x 64 cols ----
    const int lane = tid & 63;
    const int wave = tid >> 6;
    int cnt = 0;                          // wave-uniform

    #pragma unroll 1
    for (int k = 0; k < 4; ++k) {
        const int u     = wave * 4 + k;   // 0..15
        const int rg    = u & 1;          // row-group (0..1)
        const int cg    = u >> 1;         // col-group (0..7)
        const int rbase = rg * 4;         // LDS rows rbase..rbase+7
        const int cc    = cg * 64 + lane; // this lane's center col

        // 5 shifted column indices, reflect-padded at image edges:
        // c in [-2,513] -> min(|c|, |1022-c|)
        int cx[5];
        #pragma unroll
        for (int dx = 0; dx < 5; ++dx) {
            int c = cc + dx - 2;
            int a = c < 0 ? -c : c;
            int d = 1022 - c; d = d < 0 ? -d : d;
            cx[dx] = a < d ? a : d;
        }

        // center values: rows rbase+2 .. rbase+5
        const float pc0 = lsp[rbase + 2][cc], pc1 = lsp[rbase + 3][cc],
                    pc2 = lsp[rbase + 4][cc], pc3 = lsp[rbase + 5][cc];
        const float gc0 = lsg[rbase + 2][cc], gc1 = lsg[rbase + 3][cc],
                    gc2 = lsg[rbase + 4][cc], gc3 = lsg[rbase + 5][cc];

        // one ds_read per (row,dx) serves up to 4 center rows
        #pragma unroll
        for (int r = 0; r < 8; ++r) {
            #pragma unroll
            for (int dx = 0; dx < 5; ++dx) {
                const float pv = lsp[rbase + r][cx[dx]];
                const float gv = lsg[rbase + r][cx[dx]];
                #pragma unroll
                for (int j = 0; j < 4; ++j) {
                    const int dy = r - 2 - j;         // window row offset
                    if (dy < -2 || dy > 2) continue;  // out of 5x5 window
                    if (dy == 0 && dx == 2) continue; // window center
                    const float pc = (j == 0) ? pc0 : (j == 1) ? pc1
                                   : (j == 2) ? pc2 : pc3;
                    const float gc = (j == 0) ? gc0 : (j == 1) ? gc1
                                   : (j == 2) ? gc2 : gc3;
                    unsigned long long pm = BALLOT(pv < pc);
                    unsigned long long gm = BALLOT(gv < gc);
                    cnt += __builtin_popcountll(pm ^ gm);
                }
            }
        }
    }

    // ---- block reduction: cnt is wave-uniform ----
    if (lane == 0) wave_sums[wave] = cnt;
    __syncthreads();

    if (tid == 0) {
        int total = wave_sums[0] + wave_sums[1] + wave_sums[2] + wave_sums[3];
        atomicAdd(&ws[0], (unsigned int)total);
        __threadfence();
        unsigned int r = atomicAdd(&ws[1], 1u);
        if (r == (unsigned int)(NBLOCKS - 1)) {
            unsigned int tot = atomicAdd(&ws[0], 0u);
            out[0] = (float)((double)tot / (double)NPIX);
        }
    }
}

extern "C" void kernel_launch(void* const* d_in, const int* in_sizes, int n_in,
                              void* d_out, int out_size, void* d_ws, size_t ws_size,
                              hipStream_t stream) {
    const float* pred = (const float*)d_in[0];
    const float* gt   = (const float*)d_in[1];
    float* out        = (float*)d_out;
    unsigned int* ws  = (unsigned int*)d_ws;

    census_init<<<1, 1, 0, stream>>>(ws);
    census_main<<<NBLOCKS, BLOCK, 0, stream>>>(pred, gt, out, ws);
}